// Round 5
// baseline (317.852 us; speedup 1.0000x reference)
//
#include <hip/hip_runtime.h>
#include <hip/hip_cooperative_groups.h>

namespace cg = cooperative_groups;

typedef unsigned short u16;
typedef short bf16x8 __attribute__((ext_vector_type(8)));
typedef float f32x4 __attribute__((ext_vector_type(4)));

#define BB 8
#define CC 768
#define NN 256
#define HH 12
#define DD 64
#define K3 3072          // H*N
#define BCN 196608       // C*N per batch
#define SCALE 0.125f
#define LDP 72           // LDS pitch (u16): 144B rows, 16B-aligned, 2-way banks only
#define NBLK 384

__device__ __forceinline__ u16 f2b(float f) {
    union { float f; unsigned int i; } v; v.f = f;
    unsigned int r = v.i + 0x7FFFu + ((v.i >> 16) & 1u);
    return (u16)(r >> 16);
}

// ---------------------------------------------------------------------------
// Single fused cooperative kernel. 384 blocks x 256 threads, 4 grid syncs.
//   Phase 0: crT[b][n][c], xT[b][m][d] transposes (bf16, into d_out scratch);
//            zero G. Phase 1: cp = Wp*cross+bp (bf16, ws). Phase 2: G = M^T
//            Gram w/ split-K atomics. Phase 3: U = xT*G (bf16, aliases cp).
//            Phase 4: out = x + bd + Wd*U2 (f32, overwrites d_out scratch).
// All GEMMs NT-form MFMA 16x16x32_bf16, 64x64x64 tiles, bodies identical to
// the verified round-4 kernels.
// ---------------------------------------------------------------------------
__global__ __launch_bounds__(256) void k_fused(
    const float* __restrict__ x, const float* __restrict__ cross,
    const float* __restrict__ Wp, const float* __restrict__ bp,
    const float* __restrict__ Wd, const float* __restrict__ bd,
    char* outbase, char* ws)
{
    __shared__ __align__(16) u16 SMEM[2 * 64 * LDP];   // 18432 B
    u16* As = SMEM;
    u16* Bs = SMEM + 64 * LDP;
    float (*T)[68] = reinterpret_cast<float(*)[68]>(SMEM);  // 17408 B overlay

    float* out = (float*)outbase;
    u16*   crT = (u16*)outbase;                    // [8][256][768] scratch
    u16*   xT  = crT + (size_t)BB * BCN;           // [8][3072][64] scratch
    u16*   cp  = (u16*)ws;                         // [8][768][256] bf16; U aliases
    u16*   U   = cp;
    float* G   = (float*)(ws + (size_t)BB * BCN * sizeof(u16));  // [8][64][64]

    const int blk = blockIdx.x;
    const int t = threadIdx.x;
    const int lane = t & 63, wave = t >> 6;
    const int q = lane >> 4, tx = lane & 15;
    const int wm = (wave & 1) * 32, wn = (wave >> 1) * 32;
    cg::grid_group grid = cg::this_grid();

    // ================= Phase 0: transposes + zero G =================
    if (blk < BB) {  // zero G[blk]
        float* Gb = G + blk * 4096;
        #pragma unroll
        for (int j = 0; j < 4; ++j) {
            float4 z = {0.f, 0.f, 0.f, 0.f};
            *reinterpret_cast<float4*>(Gb + (t * 4 + j * 1024)) = z;
        }
    }
    #pragma unroll
    for (int jj = 0; jj < 2; ++jj) {
        const int j  = blk * 2 + jj;          // 0..767
        const int n0 = (j & 3) * 64;
        const int yy = (j >> 2) % 24;
        const int b  = j / 96;
        if (yy < HH) {
            const int h = yy;
            const float* xb = x + b * BCN;
            {   // load 64 d-rows (c = d*12+h) x 64 n
                const int d = t >> 2, fq = t & 3;
                const float* src = xb + (d * HH + h) * NN + n0;
                #pragma unroll
                for (int u = 0; u < 4; ++u) {
                    const int nl = (fq + 4 * u) * 4;
                    float4 v = *reinterpret_cast<const float4*>(src + nl);
                    T[d][nl + 0] = v.x; T[d][nl + 1] = v.y; T[d][nl + 2] = v.z; T[d][nl + 3] = v.w;
                }
            }
            __syncthreads();
            {   // xT[(h*256+n0+nn)*64 + d]
                const int nn = t >> 2, dq = t & 3;
                u16* dst = xT + b * BCN + (h * NN + n0 + nn) * DD;
                #pragma unroll
                for (int u = 0; u < 4; ++u) {
                    const int d0 = (dq + 4 * u) * 4;
                    ushort4 w;
                    w.x = f2b(T[d0 + 0][nn]); w.y = f2b(T[d0 + 1][nn]);
                    w.z = f2b(T[d0 + 2][nn]); w.w = f2b(T[d0 + 3][nn]);
                    *reinterpret_cast<ushort4*>(dst + d0) = w;
                }
            }
        } else {
            const int c0 = (yy - HH) * 64;
            const float* crb = cross + b * BCN;
            {
                const int r = t >> 2, fq = t & 3;
                const float* src = crb + (c0 + r) * NN + n0;
                #pragma unroll
                for (int u = 0; u < 4; ++u) {
                    const int nl = (fq + 4 * u) * 4;
                    float4 v = *reinterpret_cast<const float4*>(src + nl);
                    T[r][nl + 0] = v.x; T[r][nl + 1] = v.y; T[r][nl + 2] = v.z; T[r][nl + 3] = v.w;
                }
            }
            __syncthreads();
            {
                const int nn = t >> 2, cq = t & 3;
                u16* dst = crT + b * BCN + (n0 + nn) * CC + c0;
                #pragma unroll
                for (int u = 0; u < 4; ++u) {
                    const int cl = (cq + 4 * u) * 4;
                    ushort4 w;
                    w.x = f2b(T[cl + 0][nn]); w.y = f2b(T[cl + 1][nn]);
                    w.z = f2b(T[cl + 2][nn]); w.w = f2b(T[cl + 3][nn]);
                    *reinterpret_cast<ushort4*>(dst + cl) = w;
                }
            }
        }
        __syncthreads();
    }

    grid.sync();

    // ================= Phase 1: cp = Wp*cross + bp =================
    {
        const int n0 = (blk & 3) * 64;
        const int o0 = ((blk >> 2) % 12) * 64;
        const int b  = blk / 48;
        const u16* crTb = crT + b * BCN;
        f32x4 acc[2][2] = {};
        for (int c0 = 0; c0 < CC; c0 += 64) {
            {   // A: Wp[o0+r][c0..+64) cvt
                const int r = t >> 2, cq = t & 3;
                const float* src = Wp + (o0 + r) * CC + c0;
                u16* dst = As + r * LDP;
                #pragma unroll
                for (int u = 0; u < 4; ++u) {
                    const int cl = (cq + 4 * u) * 4;
                    float4 v = *reinterpret_cast<const float4*>(src + cl);
                    ushort4 w; w.x = f2b(v.x); w.y = f2b(v.y); w.z = f2b(v.z); w.w = f2b(v.w);
                    *reinterpret_cast<ushort4*>(dst + cl) = w;
                }
            }
            {   // B: crT[n0+r][c0..+64) copy
                const int r = t >> 3, ch = (t & 7) * 8;
                *reinterpret_cast<uint4*>(Bs + r * LDP + ch) =
                    *reinterpret_cast<const uint4*>(crTb + (n0 + r) * CC + c0 + ch);
                *reinterpret_cast<uint4*>(Bs + (r + 32) * LDP + ch) =
                    *reinterpret_cast<const uint4*>(crTb + (n0 + r + 32) * CC + c0 + ch);
            }
            __syncthreads();
            #pragma unroll
            for (int kk = 0; kk < 2; ++kk) {
                bf16x8 a0 = *reinterpret_cast<bf16x8*>(As + (wm + tx) * LDP + kk * 32 + q * 8);
                bf16x8 a1 = *reinterpret_cast<bf16x8*>(As + (wm + 16 + tx) * LDP + kk * 32 + q * 8);
                bf16x8 b0 = *reinterpret_cast<bf16x8*>(Bs + (wn + tx) * LDP + kk * 32 + q * 8);
                bf16x8 b1 = *reinterpret_cast<bf16x8*>(Bs + (wn + 16 + tx) * LDP + kk * 32 + q * 8);
                acc[0][0] = __builtin_amdgcn_mfma_f32_16x16x32_bf16(a0, b0, acc[0][0], 0, 0, 0);
                acc[0][1] = __builtin_amdgcn_mfma_f32_16x16x32_bf16(a0, b1, acc[0][1], 0, 0, 0);
                acc[1][0] = __builtin_amdgcn_mfma_f32_16x16x32_bf16(a1, b0, acc[1][0], 0, 0, 0);
                acc[1][1] = __builtin_amdgcn_mfma_f32_16x16x32_bf16(a1, b1, acc[1][1], 0, 0, 0);
            }
            __syncthreads();
        }
        u16* cpb = cp + b * BCN;
        #pragma unroll
        for (int i = 0; i < 2; ++i)
            #pragma unroll
            for (int j2 = 0; j2 < 2; ++j2)
                #pragma unroll
                for (int r = 0; r < 4; ++r) {
                    const int o = o0 + wm + i * 16 + q * 4 + r;
                    const int n = n0 + wn + j2 * 16 + tx;
                    cpb[o * NN + n] = f2b(acc[i][j2][r] + bp[o]);
                }
    }

    grid.sync();

    // ================= Phase 2: G[dd][d] += SCALE * cross_v[dd]*cp_v[d] =====
    {
        const int kb = (blk % 48) * 64;
        const int b  = blk / 48;
        const float* crb = cross + b * BCN;
        const u16* cpb = cp + b * BCN;
        f32x4 acc[2][2] = {};
        {
            const int r = t >> 2, cq = t & 3;
            const float* src = crb + r * K3 + kb;
            u16* dst = As + r * LDP;
            #pragma unroll
            for (int u = 0; u < 4; ++u) {
                const int cl = (cq + 4 * u) * 4;
                float4 v = *reinterpret_cast<const float4*>(src + cl);
                ushort4 w; w.x = f2b(v.x); w.y = f2b(v.y); w.z = f2b(v.z); w.w = f2b(v.w);
                *reinterpret_cast<ushort4*>(dst + cl) = w;
            }
        }
        {
            const int r = t >> 3, ch = (t & 7) * 8;
            *reinterpret_cast<uint4*>(Bs + r * LDP + ch) =
                *reinterpret_cast<const uint4*>(cpb + r * K3 + kb + ch);
            *reinterpret_cast<uint4*>(Bs + (r + 32) * LDP + ch) =
                *reinterpret_cast<const uint4*>(cpb + (r + 32) * K3 + kb + ch);
        }
        __syncthreads();
        #pragma unroll
        for (int kk = 0; kk < 2; ++kk) {
            bf16x8 a0 = *reinterpret_cast<bf16x8*>(As + (wm + tx) * LDP + kk * 32 + q * 8);
            bf16x8 a1 = *reinterpret_cast<bf16x8*>(As + (wm + 16 + tx) * LDP + kk * 32 + q * 8);
            bf16x8 b0 = *reinterpret_cast<bf16x8*>(Bs + (wn + tx) * LDP + kk * 32 + q * 8);
            bf16x8 b1 = *reinterpret_cast<bf16x8*>(Bs + (wn + 16 + tx) * LDP + kk * 32 + q * 8);
            acc[0][0] = __builtin_amdgcn_mfma_f32_16x16x32_bf16(a0, b0, acc[0][0], 0, 0, 0);
            acc[0][1] = __builtin_amdgcn_mfma_f32_16x16x32_bf16(a0, b1, acc[0][1], 0, 0, 0);
            acc[1][0] = __builtin_amdgcn_mfma_f32_16x16x32_bf16(a1, b0, acc[1][0], 0, 0, 0);
            acc[1][1] = __builtin_amdgcn_mfma_f32_16x16x32_bf16(a1, b1, acc[1][1], 0, 0, 0);
        }
        __syncthreads();
        float* Gb = G + b * 4096;
        #pragma unroll
        for (int i = 0; i < 2; ++i)
            #pragma unroll
            for (int j2 = 0; j2 < 2; ++j2)
                #pragma unroll
                for (int r = 0; r < 4; ++r) {
                    const int dd = wm + i * 16 + q * 4 + r;
                    const int d  = wn + j2 * 16 + tx;
                    atomicAdd(Gb + dd * DD + d, acc[i][j2][r] * SCALE);
                }
    }

    grid.sync();

    // ================= Phase 3: U[m][dd] = xT[m][:] . G[dd][:] ==============
    {
        const int m0 = (blk % 48) * 64;
        const int b  = blk / 48;
        const u16* xTb = xT + b * BCN;
        const float* Gb = G + b * 4096;
        f32x4 acc[2][2] = {};
        {
            const int r = t >> 3, ch = (t & 7) * 8;
            *reinterpret_cast<uint4*>(As + r * LDP + ch) =
                *reinterpret_cast<const uint4*>(xTb + (m0 + r) * DD + ch);
            *reinterpret_cast<uint4*>(As + (r + 32) * LDP + ch) =
                *reinterpret_cast<const uint4*>(xTb + (m0 + r + 32) * DD + ch);
        }
        {
            const int r = t >> 2, cq = t & 3;
            const float* src = Gb + r * DD;
            u16* dst = Bs + r * LDP;
            #pragma unroll
            for (int u = 0; u < 4; ++u) {
                const int cl = (cq + 4 * u) * 4;
                float4 v = *reinterpret_cast<const float4*>(src + cl);
                ushort4 w; w.x = f2b(v.x); w.y = f2b(v.y); w.z = f2b(v.z); w.w = f2b(v.w);
                *reinterpret_cast<ushort4*>(dst + cl) = w;
            }
        }
        __syncthreads();
        #pragma unroll
        for (int kk = 0; kk < 2; ++kk) {
            bf16x8 a0 = *reinterpret_cast<bf16x8*>(As + (wm + tx) * LDP + kk * 32 + q * 8);
            bf16x8 a1 = *reinterpret_cast<bf16x8*>(As + (wm + 16 + tx) * LDP + kk * 32 + q * 8);
            bf16x8 b0 = *reinterpret_cast<bf16x8*>(Bs + (wn + tx) * LDP + kk * 32 + q * 8);
            bf16x8 b1 = *reinterpret_cast<bf16x8*>(Bs + (wn + 16 + tx) * LDP + kk * 32 + q * 8);
            acc[0][0] = __builtin_amdgcn_mfma_f32_16x16x32_bf16(a0, b0, acc[0][0], 0, 0, 0);
            acc[0][1] = __builtin_amdgcn_mfma_f32_16x16x32_bf16(a0, b1, acc[0][1], 0, 0, 0);
            acc[1][0] = __builtin_amdgcn_mfma_f32_16x16x32_bf16(a1, b0, acc[1][0], 0, 0, 0);
            acc[1][1] = __builtin_amdgcn_mfma_f32_16x16x32_bf16(a1, b1, acc[1][1], 0, 0, 0);
        }
        __syncthreads();
        // U aliases cp: safe — all phase-2 reads of cp completed before the
        // grid.sync above, and phase-4 reads U only after the next grid.sync.
        u16* Ub = U + b * BCN;
        #pragma unroll
        for (int i = 0; i < 2; ++i)
            #pragma unroll
            for (int j2 = 0; j2 < 2; ++j2)
                #pragma unroll
                for (int r = 0; r < 4; ++r) {
                    const int m  = m0 + wm + i * 16 + q * 4 + r;
                    const int dd = wn + j2 * 16 + tx;
                    Ub[m * DD + dd] = f2b(acc[i][j2][r]);
                }
    }

    grid.sync();

    // ================= Phase 4: out = x + bd + Wd*U2 ========================
    {
        const int n0 = (blk & 3) * 64;
        const int o0 = ((blk >> 2) % 12) * 64;
        const int b  = blk / 48;
        const u16* Ub = U + b * BCN;
        f32x4 acc[2][2] = {};
        for (int c0 = 0; c0 < CC; c0 += 64) {
            {
                const int r = t >> 2, cq = t & 3;
                const float* src = Wd + (o0 + r) * CC + c0;
                u16* dst = As + r * LDP;
                #pragma unroll
                for (int u = 0; u < 4; ++u) {
                    const int cl = (cq + 4 * u) * 4;
                    float4 v = *reinterpret_cast<const float4*>(src + cl);
                    ushort4 w; w.x = f2b(v.x); w.y = f2b(v.y); w.z = f2b(v.z); w.w = f2b(v.w);
                    *reinterpret_cast<ushort4*>(dst + cl) = w;
                }
            }
            {
                const int r = t >> 3, ch = (t & 7) * 8;
                *reinterpret_cast<uint4*>(Bs + r * LDP + ch) =
                    *reinterpret_cast<const uint4*>(Ub + (n0 + r) * CC + c0 + ch);
                *reinterpret_cast<uint4*>(Bs + (r + 32) * LDP + ch) =
                    *reinterpret_cast<const uint4*>(Ub + (n0 + r + 32) * CC + c0 + ch);
            }
            __syncthreads();
            #pragma unroll
            for (int kk = 0; kk < 2; ++kk) {
                bf16x8 a0 = *reinterpret_cast<bf16x8*>(As + (wm + tx) * LDP + kk * 32 + q * 8);
                bf16x8 a1 = *reinterpret_cast<bf16x8*>(As + (wm + 16 + tx) * LDP + kk * 32 + q * 8);
                bf16x8 b0 = *reinterpret_cast<bf16x8*>(Bs + (wn + tx) * LDP + kk * 32 + q * 8);
                bf16x8 b1 = *reinterpret_cast<bf16x8*>(Bs + (wn + 16 + tx) * LDP + kk * 32 + q * 8);
                acc[0][0] = __builtin_amdgcn_mfma_f32_16x16x32_bf16(a0, b0, acc[0][0], 0, 0, 0);
                acc[0][1] = __builtin_amdgcn_mfma_f32_16x16x32_bf16(a0, b1, acc[0][1], 0, 0, 0);
                acc[1][0] = __builtin_amdgcn_mfma_f32_16x16x32_bf16(a1, b0, acc[1][0], 0, 0, 0);
                acc[1][1] = __builtin_amdgcn_mfma_f32_16x16x32_bf16(a1, b1, acc[1][1], 0, 0, 0);
            }
            __syncthreads();
        }
        #pragma unroll
        for (int i = 0; i < 2; ++i)
            #pragma unroll
            for (int j2 = 0; j2 < 2; ++j2)
                #pragma unroll
                for (int r = 0; r < 4; ++r) {
                    const int o = o0 + wm + i * 16 + q * 4 + r;
                    const int n = n0 + wn + j2 * 16 + tx;
                    const int idx = b * BCN + o * NN + n;
                    out[idx] = acc[i][j2][r] + bd[o] + x[idx];
                }
    }
}

extern "C" void kernel_launch(void* const* d_in, const int* in_sizes, int n_in,
                              void* d_out, int out_size, void* d_ws, size_t ws_size,
                              hipStream_t stream) {
    const float* x_ori = (const float*)d_in[0];
    const float* cross = (const float*)d_in[1];
    const float* Wp    = (const float*)d_in[2];
    const float* bp    = (const float*)d_in[3];
    const float* Wd    = (const float*)d_in[4];
    const float* bd    = (const float*)d_in[5];
    char* outbase = (char*)d_out;
    char* ws      = (char*)d_ws;

    void* args[] = { (void*)&x_ori, (void*)&cross, (void*)&Wp, (void*)&bp,
                     (void*)&Wd, (void*)&bd, (void*)&outbase, (void*)&ws };
    hipLaunchCooperativeKernel((const void*)k_fused, dim3(NBLK), dim3(256),
                               args, 0, stream);
}

// Round 6
// 124.373 us; speedup vs baseline: 2.5556x; 2.5556x over previous
//
#include <hip/hip_runtime.h>

typedef unsigned short u16;
typedef short bf16x8 __attribute__((ext_vector_type(8)));
typedef float f32x4 __attribute__((ext_vector_type(4)));

#define BB 8
#define CC 768
#define NN 256
#define HH 12
#define DD 64
#define K3 3072          // H*N
#define BCN 196608       // C*N per batch
#define SCALE 0.125f
#define LDP 72           // LDS pitch (u16): 144B rows, 16B-aligned, 2-way banks only

__device__ __forceinline__ u16 f2b(float f) {
    union { float f; unsigned int i; } v; v.f = f;
    unsigned int r = v.i + 0x7FFFu + ((v.i >> 16) & 1u);
    return (u16)(r >> 16);
}

// ---------------------------------------------------------------------------
// Stage 1: cp[b,o,n] = sum_c Wp[o,c]*cross[b,c,n] + bp[o]     (bf16 out)
// NT-MFMA 64x64x64 tiles. B-tile (cross^T) built in-kernel: coalesced f32
// loads into LDS tile T, transposed+cvt re-read into Bs. Blocks (0,0,b) also
// zero G[b] (consumed by k_gram next dispatch — stream-ordered).
// ---------------------------------------------------------------------------
__global__ __launch_bounds__(256) void k_proj(
    const float* __restrict__ Wp, const float* __restrict__ cross,
    const float* __restrict__ bp, u16* __restrict__ cp, float* __restrict__ G)
{
    __shared__ __align__(16) u16 As[64 * LDP];
    __shared__ __align__(16) u16 Bs[64 * LDP];
    __shared__ __align__(16) float T[64][68];
    const int n0 = blockIdx.x * 64;
    const int o0 = blockIdx.y * 64;
    const int b  = blockIdx.z;
    const int t = threadIdx.x;
    const int lane = t & 63, wave = t >> 6;
    const int q = lane >> 4, tx = lane & 15;
    const int wm = (wave & 1) * 32, wn = (wave >> 1) * 32;

    if (blockIdx.x == 0 && blockIdx.y == 0) {   // zero G[b]
        float4 z = {0.f, 0.f, 0.f, 0.f};
        float* Gb = G + b * 4096;
        #pragma unroll
        for (int j = 0; j < 4; ++j)
            *reinterpret_cast<float4*>(Gb + t * 4 + j * 1024) = z;
    }

    const float* crb = cross + b * BCN;
    f32x4 acc[2][2] = {};
    for (int c0 = 0; c0 < CC; c0 += 64) {
        {   // A: Wp[o0+r][c0..+64) f32->bf16
            const int r = t >> 2, cq = t & 3;
            const float* src = Wp + (o0 + r) * CC + c0;
            u16* dst = As + r * LDP;
            #pragma unroll
            for (int u = 0; u < 4; ++u) {
                const int cl = (cq + 4 * u) * 4;
                float4 v = *reinterpret_cast<const float4*>(src + cl);
                ushort4 w; w.x = f2b(v.x); w.y = f2b(v.y); w.z = f2b(v.z); w.w = f2b(v.w);
                *reinterpret_cast<ushort4*>(dst + cl) = w;
            }
        }
        {   // T: cross[c0+r][n0..+64) coalesced f32
            const int r = t >> 2, fq = t & 3;
            const float* src = crb + (c0 + r) * NN + n0;
            #pragma unroll
            for (int u = 0; u < 4; ++u) {
                const int nl = (fq + 4 * u) * 4;
                float4 v = *reinterpret_cast<const float4*>(src + nl);
                T[r][nl + 0] = v.x; T[r][nl + 1] = v.y; T[r][nl + 2] = v.z; T[r][nl + 3] = v.w;
            }
        }
        __syncthreads();
        {   // Bs[n][c] = cvt(T[c][n])  (transpose; T col reads are 2-way = free)
            const int nn = t >> 2, cq = t & 3;
            u16* dst = Bs + nn * LDP;
            #pragma unroll
            for (int u = 0; u < 4; ++u) {
                const int c4 = (cq + 4 * u) * 4;
                ushort4 w;
                w.x = f2b(T[c4 + 0][nn]); w.y = f2b(T[c4 + 1][nn]);
                w.z = f2b(T[c4 + 2][nn]); w.w = f2b(T[c4 + 3][nn]);
                *reinterpret_cast<ushort4*>(dst + c4) = w;
            }
        }
        __syncthreads();
        #pragma unroll
        for (int kk = 0; kk < 2; ++kk) {
            bf16x8 a0 = *reinterpret_cast<bf16x8*>(As + (wm + tx) * LDP + kk * 32 + q * 8);
            bf16x8 a1 = *reinterpret_cast<bf16x8*>(As + (wm + 16 + tx) * LDP + kk * 32 + q * 8);
            bf16x8 b0 = *reinterpret_cast<bf16x8*>(Bs + (wn + tx) * LDP + kk * 32 + q * 8);
            bf16x8 b1 = *reinterpret_cast<bf16x8*>(Bs + (wn + 16 + tx) * LDP + kk * 32 + q * 8);
            acc[0][0] = __builtin_amdgcn_mfma_f32_16x16x32_bf16(a0, b0, acc[0][0], 0, 0, 0);
            acc[0][1] = __builtin_amdgcn_mfma_f32_16x16x32_bf16(a0, b1, acc[0][1], 0, 0, 0);
            acc[1][0] = __builtin_amdgcn_mfma_f32_16x16x32_bf16(a1, b0, acc[1][0], 0, 0, 0);
            acc[1][1] = __builtin_amdgcn_mfma_f32_16x16x32_bf16(a1, b1, acc[1][1], 0, 0, 0);
        }
        __syncthreads();
    }
    u16* cpb = cp + b * BCN;
    #pragma unroll
    for (int i = 0; i < 2; ++i)
        #pragma unroll
        for (int j = 0; j < 2; ++j)
            #pragma unroll
            for (int r = 0; r < 4; ++r) {
                const int o = o0 + wm + i * 16 + q * 4 + r;
                const int n = n0 + wn + j * 16 + tx;
                cpb[o * NN + n] = f2b(acc[i][j][r] + bp[o]);
            }
}

// ---------------------------------------------------------------------------
// Stage 2: G[b][dd][d] += SCALE * sum_k cross_view[dd][k]*cp_view[d][k]
// Split-K 48 x 64 chunks, f32 atomics (G pre-zeroed by k_proj).
// ---------------------------------------------------------------------------
__global__ __launch_bounds__(256) void k_gram(
    const float* __restrict__ cross, const u16* __restrict__ cp, float* __restrict__ G)
{
    __shared__ __align__(16) u16 As[64 * LDP];
    __shared__ __align__(16) u16 Bs[64 * LDP];
    const int kb = blockIdx.x * 64;
    const int b  = blockIdx.y;
    const int t = threadIdx.x;
    const int lane = t & 63, wave = t >> 6;
    const int q = lane >> 4, tx = lane & 15;
    const int wm = (wave & 1) * 32, wn = (wave >> 1) * 32;
    const float* crb = cross + b * BCN;
    const u16* cpb = cp + b * BCN;
    f32x4 acc[2][2] = {};
    {
        const int r = t >> 2, cq = t & 3;
        const float* src = crb + r * K3 + kb;
        u16* dst = As + r * LDP;
        #pragma unroll
        for (int u = 0; u < 4; ++u) {
            const int cl = (cq + 4 * u) * 4;
            float4 v = *reinterpret_cast<const float4*>(src + cl);
            ushort4 w; w.x = f2b(v.x); w.y = f2b(v.y); w.z = f2b(v.z); w.w = f2b(v.w);
            *reinterpret_cast<ushort4*>(dst + cl) = w;
        }
    }
    {
        const int r = t >> 3, ch = (t & 7) * 8;
        *reinterpret_cast<uint4*>(Bs + r * LDP + ch) =
            *reinterpret_cast<const uint4*>(cpb + r * K3 + kb + ch);
        *reinterpret_cast<uint4*>(Bs + (r + 32) * LDP + ch) =
            *reinterpret_cast<const uint4*>(cpb + (r + 32) * K3 + kb + ch);
    }
    __syncthreads();
    #pragma unroll
    for (int kk = 0; kk < 2; ++kk) {
        bf16x8 a0 = *reinterpret_cast<bf16x8*>(As + (wm + tx) * LDP + kk * 32 + q * 8);
        bf16x8 a1 = *reinterpret_cast<bf16x8*>(As + (wm + 16 + tx) * LDP + kk * 32 + q * 8);
        bf16x8 b0 = *reinterpret_cast<bf16x8*>(Bs + (wn + tx) * LDP + kk * 32 + q * 8);
        bf16x8 b1 = *reinterpret_cast<bf16x8*>(Bs + (wn + 16 + tx) * LDP + kk * 32 + q * 8);
        acc[0][0] = __builtin_amdgcn_mfma_f32_16x16x32_bf16(a0, b0, acc[0][0], 0, 0, 0);
        acc[0][1] = __builtin_amdgcn_mfma_f32_16x16x32_bf16(a0, b1, acc[0][1], 0, 0, 0);
        acc[1][0] = __builtin_amdgcn_mfma_f32_16x16x32_bf16(a1, b0, acc[1][0], 0, 0, 0);
        acc[1][1] = __builtin_amdgcn_mfma_f32_16x16x32_bf16(a1, b1, acc[1][1], 0, 0, 0);
    }
    float* Gb = G + b * 4096;
    #pragma unroll
    for (int i = 0; i < 2; ++i)
        #pragma unroll
        for (int j = 0; j < 2; ++j)
            #pragma unroll
            for (int r = 0; r < 4; ++r) {
                const int dd = wm + i * 16 + q * 4 + r;
                const int d  = wn + j * 16 + tx;
                atomicAdd(Gb + dd * DD + d, acc[i][j][r] * SCALE);
            }
}

// ---------------------------------------------------------------------------
// Stage 3: U[b][m][dd] = sum_d xT[m][d]*G[dd][d].  A-tile (x^T) built
// in-kernel via LDS f32 tile T. U (bf16) aliases cp. 48 m-tiles x 8 batches.
// ---------------------------------------------------------------------------
__global__ __launch_bounds__(256) void k_xm(
    const float* __restrict__ x, const float* __restrict__ G, u16* __restrict__ U)
{
    __shared__ __align__(16) u16 As[64 * LDP];
    __shared__ __align__(16) u16 Bs[64 * LDP];
    __shared__ __align__(16) float T[64][68];
    const int m0 = blockIdx.x * 64;
    const int b  = blockIdx.y;
    const int h   = m0 >> 8;       // head index (m = h*256 + nn)
    const int nn0 = m0 & 255;
    const int t = threadIdx.x;
    const int lane = t & 63, wave = t >> 6;
    const int q = lane >> 4, tx = lane & 15;
    const int wm = (wave & 1) * 32, wn = (wave >> 1) * 32;
    const float* xb = x + b * BCN;
    const float* Gb = G + b * 4096;
    f32x4 acc[2][2] = {};
    {   // T[d][nl] = x[(d*12+h)*256 + nn0+nl]  (coalesced rows)
        const int d = t >> 2, fq = t & 3;
        const float* src = xb + (d * HH + h) * NN + nn0;
        #pragma unroll
        for (int u = 0; u < 4; ++u) {
            const int nl = (fq + 4 * u) * 4;
            float4 v = *reinterpret_cast<const float4*>(src + nl);
            T[d][nl + 0] = v.x; T[d][nl + 1] = v.y; T[d][nl + 2] = v.z; T[d][nl + 3] = v.w;
        }
    }
    {   // Bs[dd][d] = cvt(G[dd][d])
        const int r = t >> 2, cq = t & 3;
        const float* src = Gb + r * DD;
        u16* dst = Bs + r * LDP;
        #pragma unroll
        for (int u = 0; u < 4; ++u) {
            const int cl = (cq + 4 * u) * 4;
            float4 v = *reinterpret_cast<const float4*>(src + cl);
            ushort4 w; w.x = f2b(v.x); w.y = f2b(v.y); w.z = f2b(v.z); w.w = f2b(v.w);
            *reinterpret_cast<ushort4*>(dst + cl) = w;
        }
    }
    __syncthreads();
    {   // As[m_local][d] = cvt(T[d][m_local])  (transpose)
        const int nn = t >> 2, dq = t & 3;
        u16* dst = As + nn * LDP;
        #pragma unroll
        for (int u = 0; u < 4; ++u) {
            const int d4 = (dq + 4 * u) * 4;
            ushort4 w;
            w.x = f2b(T[d4 + 0][nn]); w.y = f2b(T[d4 + 1][nn]);
            w.z = f2b(T[d4 + 2][nn]); w.w = f2b(T[d4 + 3][nn]);
            *reinterpret_cast<ushort4*>(dst + d4) = w;
        }
    }
    __syncthreads();
    #pragma unroll
    for (int kk = 0; kk < 2; ++kk) {
        bf16x8 a0 = *reinterpret_cast<bf16x8*>(As + (wm + tx) * LDP + kk * 32 + q * 8);
        bf16x8 a1 = *reinterpret_cast<bf16x8*>(As + (wm + 16 + tx) * LDP + kk * 32 + q * 8);
        bf16x8 b0 = *reinterpret_cast<bf16x8*>(Bs + (wn + tx) * LDP + kk * 32 + q * 8);
        bf16x8 b1 = *reinterpret_cast<bf16x8*>(Bs + (wn + 16 + tx) * LDP + kk * 32 + q * 8);
        acc[0][0] = __builtin_amdgcn_mfma_f32_16x16x32_bf16(a0, b0, acc[0][0], 0, 0, 0);
        acc[0][1] = __builtin_amdgcn_mfma_f32_16x16x32_bf16(a0, b1, acc[0][1], 0, 0, 0);
        acc[1][0] = __builtin_amdgcn_mfma_f32_16x16x32_bf16(a1, b0, acc[1][0], 0, 0, 0);
        acc[1][1] = __builtin_amdgcn_mfma_f32_16x16x32_bf16(a1, b1, acc[1][1], 0, 0, 0);
    }
    u16* Ub = U + b * BCN;
    #pragma unroll
    for (int i = 0; i < 2; ++i)
        #pragma unroll
        for (int j = 0; j < 2; ++j)
            #pragma unroll
            for (int r = 0; r < 4; ++r) {
                const int m  = m0 + wm + i * 16 + q * 4 + r;
                const int dd = wn + j * 16 + tx;
                Ub[m * DD + dd] = f2b(acc[i][j][r]);
            }
}

// ---------------------------------------------------------------------------
// Stage 4: out[b,o,n] = x[b,o,n] + bd[o] + sum_k Wd[o,k]*U2[n,k]
// A=Wd (f32 cvt), B=U2 = U flat viewed [256][768] (bf16, k-contig). Native NT.
// ---------------------------------------------------------------------------
__global__ __launch_bounds__(256) void k_dep(
    const float* __restrict__ Wd, const u16* __restrict__ U,
    const float* __restrict__ bd, const float* __restrict__ x, float* __restrict__ out)
{
    __shared__ __align__(16) u16 As[64 * LDP];
    __shared__ __align__(16) u16 Bs[64 * LDP];
    const int n0 = blockIdx.x * 64;
    const int o0 = blockIdx.y * 64;
    const int b  = blockIdx.z;
    const int t = threadIdx.x;
    const int lane = t & 63, wave = t >> 6;
    const int q = lane >> 4, tx = lane & 15;
    const int wm = (wave & 1) * 32, wn = (wave >> 1) * 32;
    const u16* Ub = U + b * BCN;
    f32x4 acc[2][2] = {};
    for (int c0 = 0; c0 < CC; c0 += 64) {
        {
            const int r = t >> 2, cq = t & 3;
            const float* src = Wd + (o0 + r) * CC + c0;
            u16* dst = As + r * LDP;
            #pragma unroll
            for (int u = 0; u < 4; ++u) {
                const int cl = (cq + 4 * u) * 4;
                float4 v = *reinterpret_cast<const float4*>(src + cl);
                ushort4 w; w.x = f2b(v.x); w.y = f2b(v.y); w.z = f2b(v.z); w.w = f2b(v.w);
                *reinterpret_cast<ushort4*>(dst + cl) = w;
            }
        }
        {
            const int r = t >> 3, ch = (t & 7) * 8;
            *reinterpret_cast<uint4*>(Bs + r * LDP + ch) =
                *reinterpret_cast<const uint4*>(Ub + (n0 + r) * CC + c0 + ch);
            *reinterpret_cast<uint4*>(Bs + (r + 32) * LDP + ch) =
                *reinterpret_cast<const uint4*>(Ub + (n0 + r + 32) * CC + c0 + ch);
        }
        __syncthreads();
        #pragma unroll
        for (int kk = 0; kk < 2; ++kk) {
            bf16x8 a0 = *reinterpret_cast<bf16x8*>(As + (wm + tx) * LDP + kk * 32 + q * 8);
            bf16x8 a1 = *reinterpret_cast<bf16x8*>(As + (wm + 16 + tx) * LDP + kk * 32 + q * 8);
            bf16x8 b0 = *reinterpret_cast<bf16x8*>(Bs + (wn + tx) * LDP + kk * 32 + q * 8);
            bf16x8 b1 = *reinterpret_cast<bf16x8*>(Bs + (wn + 16 + tx) * LDP + kk * 32 + q * 8);
            acc[0][0] = __builtin_amdgcn_mfma_f32_16x16x32_bf16(a0, b0, acc[0][0], 0, 0, 0);
            acc[0][1] = __builtin_amdgcn_mfma_f32_16x16x32_bf16(a0, b1, acc[0][1], 0, 0, 0);
            acc[1][0] = __builtin_amdgcn_mfma_f32_16x16x32_bf16(a1, b0, acc[1][0], 0, 0, 0);
            acc[1][1] = __builtin_amdgcn_mfma_f32_16x16x32_bf16(a1, b1, acc[1][1], 0, 0, 0);
        }
        __syncthreads();
    }
    #pragma unroll
    for (int i = 0; i < 2; ++i)
        #pragma unroll
        for (int j = 0; j < 2; ++j)
            #pragma unroll
            for (int r = 0; r < 4; ++r) {
                const int o = o0 + wm + i * 16 + q * 4 + r;
                const int n = n0 + wn + j * 16 + tx;
                const int idx = b * BCN + o * NN + n;
                out[idx] = acc[i][j][r] + bd[o] + x[idx];
            }
}

extern "C" void kernel_launch(void* const* d_in, const int* in_sizes, int n_in,
                              void* d_out, int out_size, void* d_ws, size_t ws_size,
                              hipStream_t stream) {
    const float* x_ori = (const float*)d_in[0];
    const float* cross = (const float*)d_in[1];
    const float* Wp    = (const float*)d_in[2];
    const float* bp    = (const float*)d_in[3];
    const float* Wd    = (const float*)d_in[4];
    const float* bd    = (const float*)d_in[5];
    float* out = (float*)d_out;

    // ws: [0, 3,145,728): cp bf16 [8][768][256]; ALIASED by U bf16
    //     [8][3072][64] after k_gram (cp dead, stream-serialized).
    //     [3,145,728, +131,072): G f32 [8][64][64] (zeroed by k_proj blocks).
    u16*   cp = (u16*)d_ws;
    u16*   U  = (u16*)d_ws;
    float* G  = (float*)((char*)d_ws + (size_t)BB * BCN * sizeof(u16));

    k_proj<<<dim3(4, 12, BB), 256, 0, stream>>>(Wp, cross, bp, cp, G);
    k_gram<<<dim3(48, BB), 256, 0, stream>>>(cross, cp, G);
    k_xm  <<<dim3(48, BB), 256, 0, stream>>>(x_ori, G, U);
    k_dep <<<dim3(4, 12, BB), 256, 0, stream>>>(Wd, U, bd, x_ori, out);
}